// Round 3
// baseline (760.022 us; speedup 1.0000x reference)
//
#include <hip/hip_runtime.h>
#include <math.h>

#define N_NODES 10000
#define N_EDGES 640000
#define C 128
#define BF 16

__device__ __forceinline__ float gelu_exact(float z) {
    return 0.5f * z * (1.0f + erff(z * 0.70710678118654752f));
}

// --- K1: degree counts (edges only; self-loop added later as +1) ---
__global__ void k_deg(const int* __restrict__ ei, int* __restrict__ dr, int* __restrict__ dc) {
    int e = blockIdx.x * blockDim.x + threadIdx.x;
    if (e < N_EDGES) {
        atomicAdd(&dr[ei[e]], 1);
        atomicAdd(&dc[ei[N_EDGES + e]], 1);
    }
}

// --- K2: inv sqrt degree (self-loop contributes +1) ---
__global__ void k_inv(const int* __restrict__ dr, const int* __restrict__ dc,
                      float* __restrict__ ir, float* __restrict__ ic) {
    int n = blockIdx.x * blockDim.x + threadIdx.x;
    if (n < N_NODES) {
        ir[n] = rsqrtf((float)(dr[n] + 1));
        ic[n] = rsqrtf((float)(dc[n] + 1));
    }
}

// --- K3: edge messages; one wave (64 lanes) per edge, 2 channels/lane ---
__global__ __launch_bounds__(256) void k_edge(
    const float* __restrict__ x,
    const float* __restrict__ ea,
    const float* __restrict__ ew,
    const float* __restrict__ Wb,
    const float* __restrict__ bb,
    const int* __restrict__ ei,
    const float* __restrict__ ir, const float* __restrict__ ic,
    float* __restrict__ acc)
{
    int e = blockIdx.x * 4 + (threadIdx.x >> 6);   // grid = N_EDGES/4 exactly
    int lane = threadIdx.x & 63;
    int c0 = lane * 2;

    int r = ei[e];
    int c = ei[N_EDGES + e];
    float s = ir[r] * ic[c] * ew[e];

    // 16 bond features, wave-uniform address (64 B -> 4x float4 broadcast)
    const float4* eap = (const float4*)(ea + (size_t)e * BF);
    float4 q0 = eap[0], q1 = eap[1], q2 = eap[2], q3 = eap[3];
    float af[16] = {q0.x, q0.y, q0.z, q0.w,
                    q1.x, q1.y, q1.z, q1.w,
                    q2.x, q2.y, q2.z, q2.w,
                    q3.x, q3.y, q3.z, q3.w};

    // bond encoder: emb[c0], emb[c0+1]
    float2 bbv = *(const float2*)(bb + c0);
    float e0 = bbv.x, e1 = bbv.y;
#pragma unroll
    for (int k = 0; k < BF; k++) {
        float2 wf = *(const float2*)(Wb + (size_t)k * C + c0);
        e0 = fmaf(af[k], wf.x, e0);
        e1 = fmaf(af[k], wf.y, e1);
    }

    // gather x[row], gelu, scale, scatter to acc[col]
    float2 xf = *(const float2*)(x + (size_t)r * C + c0);
    float m0 = gelu_exact(xf.x + e0) * s;
    float m1 = gelu_exact(xf.y + e1) * s;
    float* dst = acc + (size_t)c * C + c0;
    atomicAdd(dst, m0);
    atomicAdd(dst + 1, m1);
}

// --- K4: add self-loop message, then out = acc @ W_lin + b_lin (fp32 store) ---
__global__ __launch_bounds__(128) void k_final(
    const float* __restrict__ acc,
    const float* __restrict__ x,
    const float* __restrict__ ir, const float* __restrict__ ic,
    const float* __restrict__ Wl,
    const float* __restrict__ bl,
    float* __restrict__ out)
{
    int n = blockIdx.x;
    int t = threadIdx.x;
    __shared__ float sh[C];
    float sl = ir[n] * ic[n];   // self-loop norm; edge weight = 1, emb = 0
    float v = acc[(size_t)n * C + t] + gelu_exact(x[(size_t)n * C + t]) * sl;
    sh[t] = v;
    __syncthreads();
    float o = bl[t];
#pragma unroll 8
    for (int k = 0; k < C; k++) {
        o = fmaf(sh[k], Wl[(size_t)k * C + t], o);
    }
    out[(size_t)n * C + t] = o;
}

extern "C" void kernel_launch(void* const* d_in, const int* in_sizes, int n_in,
                              void* d_out, int out_size, void* d_ws, size_t ws_size,
                              hipStream_t stream) {
    const float* x  = (const float*)d_in[0];
    const float* ea = (const float*)d_in[1];
    const float* ew = (const float*)d_in[2];
    const float* Wb = (const float*)d_in[3];
    const float* bb = (const float*)d_in[4];
    const float* Wl = (const float*)d_in[5];
    const float* bl = (const float*)d_in[6];
    const int*   ei = (const int*)d_in[7];
    float* out = (float*)d_out;

    // workspace layout (4-byte elements)
    float* acc = (float*)d_ws;                 // 1,280,000 floats
    int*   dr  = (int*)d_ws + 1280000;         // 10,240 ints (padded)
    int*   dc  = dr + 10240;
    float* ir  = (float*)(dc + 10240);
    float* ic  = ir + 10240;
    size_t used = (1280000 + 4 * 10240) * sizeof(float);

    hipMemsetAsync(d_ws, 0, used, stream);
    k_deg<<<(N_EDGES + 255) / 256, 256, 0, stream>>>(ei, dr, dc);
    k_inv<<<(N_NODES + 255) / 256, 256, 0, stream>>>(dr, dc, ir, ic);
    k_edge<<<N_EDGES / 4, 256, 0, stream>>>(x, ea, ew, Wb, bb, ei, ir, ic, acc);
    k_final<<<N_NODES, C, 0, stream>>>(acc, x, ir, ic, Wl, bl, out);
}

// Round 4
// 481.429 us; speedup vs baseline: 1.5787x; 1.5787x over previous
//
#include <hip/hip_runtime.h>
#include <math.h>

#define N_NODES 10000
#define N_EDGES 640000
#define C 128
#define BF 16

__device__ __forceinline__ float gelu_exact(float z) {
    return 0.5f * z * (1.0f + erff(z * 0.70710678118654752f));
}

// --- K1: degree counts (edges only; self-loop added later as +1) ---
__global__ void k_deg(const int* __restrict__ ei, int* __restrict__ dr, int* __restrict__ dc) {
    int e = blockIdx.x * blockDim.x + threadIdx.x;
    if (e < N_EDGES) {
        atomicAdd(&dr[ei[e]], 1);
        atomicAdd(&dc[ei[N_EDGES + e]], 1);
    }
}

// --- K2: single-block exclusive scan of dc -> off, plus inv-sqrt degrees ---
__global__ __launch_bounds__(256) void k_scan(
    const int* __restrict__ dr, const int* __restrict__ dc,
    int* __restrict__ off, float* __restrict__ ir, float* __restrict__ ic)
{
    __shared__ int sh[256];
    __shared__ int carry;
    if (threadIdx.x == 0) carry = 0;
    __syncthreads();
    for (int base = 0; base < N_NODES; base += 256) {
        int i = base + threadIdx.x;
        int v = (i < N_NODES) ? dc[i] : 0;
        sh[threadIdx.x] = v;
        __syncthreads();
        // inclusive scan over 256 in LDS
        for (int s = 1; s < 256; s <<= 1) {
            int t = 0;
            if (threadIdx.x >= s) t = sh[threadIdx.x - s];
            __syncthreads();
            sh[threadIdx.x] += t;
            __syncthreads();
        }
        int incl = sh[threadIdx.x];
        if (i < N_NODES) {
            off[i] = carry + incl - v;               // exclusive
            ir[i] = rsqrtf((float)(dr[i] + 1));
            ic[i] = rsqrtf((float)(v + 1));
        }
        __syncthreads();
        if (threadIdx.x == 255) carry += sh[255];
        __syncthreads();
    }
    if (threadIdx.x == 0) off[N_NODES] = carry;      // = N_EDGES
}

// --- K3: scatter edge ids into destination buckets ---
__global__ void k_scatter(const int* __restrict__ ei, const int* __restrict__ off,
                          int* __restrict__ cur, int* __restrict__ bucket) {
    int e = blockIdx.x * blockDim.x + threadIdx.x;
    if (e < N_EDGES) {
        int c = ei[N_EDGES + e];
        int pos = atomicAdd(&cur[c], 1);
        bucket[off[c] + pos] = e;
    }
}

// --- K4: one block (128 thr) per node: aggregate in-edges in registers,
//          add self-loop, then fused GEMV (@ W_lin + b_lin), no atomics ---
__global__ __launch_bounds__(128) void k_node(
    const float* __restrict__ x,
    const float* __restrict__ ea,
    const float* __restrict__ ew,
    const float* __restrict__ Wb,
    const float* __restrict__ bb,
    const int* __restrict__ ei,
    const float* __restrict__ ir, const float* __restrict__ ic,
    const int* __restrict__ off, const int* __restrict__ bucket,
    const float* __restrict__ Wl,
    const float* __restrict__ bl,
    float* __restrict__ out)
{
    int n = blockIdx.x;
    int t = threadIdx.x;          // channel 0..127

    float icn = ic[n];
    // self-loop: emb = 0, weight = 1, norm = ir[n]*ic[n]
    float acc = gelu_exact(x[(size_t)n * C + t]) * (ir[n] * icn);

    int o0 = off[n];
    int deg = off[n + 1] - o0;

    // per-channel column of W_bond: Wb[k][t], k = 0..15 (hoisted, L1-resident)
    float wb[BF];
#pragma unroll
    for (int k = 0; k < BF; k++) wb[k] = Wb[(size_t)k * C + t];
    float bbt = bb[t];

    for (int i = 0; i < deg; i++) {
        int e = bucket[o0 + i];
        e = __builtin_amdgcn_readfirstlane(e);       // wave-uniform hint
        int r = ei[e];
        float s = ir[r] * icn * ew[e];

        const float4* eap = (const float4*)(ea + (size_t)e * BF);
        float4 q0 = eap[0], q1 = eap[1], q2 = eap[2], q3 = eap[3];

        float emb = bbt;
        emb = fmaf(q0.x, wb[0], emb);  emb = fmaf(q0.y, wb[1], emb);
        emb = fmaf(q0.z, wb[2], emb);  emb = fmaf(q0.w, wb[3], emb);
        emb = fmaf(q1.x, wb[4], emb);  emb = fmaf(q1.y, wb[5], emb);
        emb = fmaf(q1.z, wb[6], emb);  emb = fmaf(q1.w, wb[7], emb);
        emb = fmaf(q2.x, wb[8], emb);  emb = fmaf(q2.y, wb[9], emb);
        emb = fmaf(q2.z, wb[10], emb); emb = fmaf(q2.w, wb[11], emb);
        emb = fmaf(q3.x, wb[12], emb); emb = fmaf(q3.y, wb[13], emb);
        emb = fmaf(q3.z, wb[14], emb); emb = fmaf(q3.w, wb[15], emb);

        float xv = x[(size_t)r * C + t];             // coalesced 512 B gather
        acc = fmaf(gelu_exact(xv + emb), s, acc);
    }

    // fused epilogue: out[n] = acc_vec @ W_lin + b_lin
    __shared__ float sh[C];
    sh[t] = acc;
    __syncthreads();
    float o = bl[t];
#pragma unroll 8
    for (int k = 0; k < C; k++) {
        o = fmaf(sh[k], Wl[(size_t)k * C + t], o);
    }
    out[(size_t)n * C + t] = o;
}

extern "C" void kernel_launch(void* const* d_in, const int* in_sizes, int n_in,
                              void* d_out, int out_size, void* d_ws, size_t ws_size,
                              hipStream_t stream) {
    const float* x  = (const float*)d_in[0];
    const float* ea = (const float*)d_in[1];
    const float* ew = (const float*)d_in[2];
    const float* Wb = (const float*)d_in[3];
    const float* bb = (const float*)d_in[4];
    const float* Wl = (const float*)d_in[5];
    const float* bl = (const float*)d_in[6];
    const int*   ei = (const int*)d_in[7];
    float* out = (float*)d_out;

    // workspace layout (4-byte units)
    int*   bucket = (int*)d_ws;            // 640,000
    int*   off    = bucket + 640000;       // 10,304 (needs 10,001)
    int*   dr     = off + 10304;           // 10,240
    int*   dc     = dr + 10240;            // 10,240
    int*   cur    = dc + 10240;            // 10,240
    float* ir     = (float*)(cur + 10240); // 10,240
    float* ic     = ir + 10240;            // 10,240

    // zero only dr, dc, cur (contiguous)
    hipMemsetAsync(dr, 0, 3 * 10240 * sizeof(int), stream);
    k_deg<<<(N_EDGES + 255) / 256, 256, 0, stream>>>(ei, dr, dc);
    k_scan<<<1, 256, 0, stream>>>(dr, dc, off, ir, ic);
    k_scatter<<<(N_EDGES + 255) / 256, 256, 0, stream>>>(ei, off, cur, bucket);
    k_node<<<N_NODES, C, 0, stream>>>(x, ea, ew, Wb, bb, ei, ir, ic, off, bucket, Wl, bl, out);
}

// Round 5
// 447.721 us; speedup vs baseline: 1.6975x; 1.0753x over previous
//
#include <hip/hip_runtime.h>
#include <hip/hip_bf16.h>
#include <math.h>

#define N_NODES 10000
#define N_EDGES 640000
#define C 128
#define BF 16

__device__ __forceinline__ float gelu_exact(float z) {
    return 0.5f * z * (1.0f + erff(z * 0.70710678118654752f));
}

// --- K0: convert x to bf16 (2.56 MB -> L2-resident under streaming) ---
__global__ __launch_bounds__(256) void k_cvt(const float* __restrict__ x,
                                             __hip_bfloat16* __restrict__ xb) {
    int i = (blockIdx.x * 256 + threadIdx.x) * 4;   // grid covers 1,280,000 exactly
    float4 v = *(const float4*)(x + i);
    xb[i + 0] = __float2bfloat16(v.x);
    xb[i + 1] = __float2bfloat16(v.y);
    xb[i + 2] = __float2bfloat16(v.z);
    xb[i + 3] = __float2bfloat16(v.w);
}

// --- K1: degree counts (edges only; self-loop added later as +1) ---
__global__ void k_deg(const int* __restrict__ ei, int* __restrict__ dr, int* __restrict__ dc) {
    int e = blockIdx.x * blockDim.x + threadIdx.x;
    if (e < N_EDGES) {
        atomicAdd(&dr[ei[e]], 1);
        atomicAdd(&dc[ei[N_EDGES + e]], 1);
    }
}

// --- K2: exclusive scan of dc -> off, plus inv-sqrt degrees (1 block, 1024 thr) ---
__global__ __launch_bounds__(1024) void k_scan(
    const int* __restrict__ dr, const int* __restrict__ dc,
    int* __restrict__ off, float* __restrict__ ir, float* __restrict__ ic)
{
    __shared__ int shp[1024];
    int t = threadIdx.x;
    int base = t * 10;                       // 10240 slots cover 10000
    int loc[10];
    int s = 0;
#pragma unroll
    for (int j = 0; j < 10; j++) {
        int i = base + j;
        int v = (i < N_NODES) ? dc[i] : 0;
        loc[j] = s;
        s += v;
    }
    shp[t] = s;
    __syncthreads();
    for (int st = 1; st < 1024; st <<= 1) {
        int a = (t >= st) ? shp[t - st] : 0;
        __syncthreads();
        shp[t] += a;
        __syncthreads();
    }
    int excl = shp[t] - s;                   // exclusive prefix of this thread's chunk
#pragma unroll
    for (int j = 0; j < 10; j++) {
        int i = base + j;
        if (i < N_NODES) {
            off[i] = excl + loc[j];
            ir[i] = rsqrtf((float)(dr[i] + 1));
            ic[i] = rsqrtf((float)(dc[i] + 1));
        }
    }
    if (t == 1023) off[N_NODES] = shp[1023];
}

// --- K3: scatter edge ids into destination buckets ---
__global__ void k_scatter(const int* __restrict__ ei, const int* __restrict__ off,
                          int* __restrict__ cur, int* __restrict__ bucket) {
    int e = blockIdx.x * blockDim.x + threadIdx.x;
    if (e < N_EDGES) {
        int c = ei[N_EDGES + e];
        int pos = atomicAdd(&cur[c], 1);
        bucket[off[c] + pos] = e;
    }
}

// --- K4: one block (512 thr = 4 edge-groups x 128 channels) per node ---
template <bool USEBF>
__global__ __launch_bounds__(512) void k_node(
    const float* __restrict__ x,
    const __hip_bfloat16* __restrict__ xb,
    const float* __restrict__ ea,
    const float* __restrict__ ew,
    const float* __restrict__ Wb,
    const float* __restrict__ bb,
    const int* __restrict__ ei,
    const float* __restrict__ ir, const float* __restrict__ ic,
    const int* __restrict__ off, const int* __restrict__ bucket,
    const float* __restrict__ Wl,
    const float* __restrict__ bl,
    float* __restrict__ out)
{
    int n = blockIdx.x;
    int t = threadIdx.x & (C - 1);           // channel
    int g = threadIdx.x >> 7;                // edge group 0..3

    float icn = ic[n];

    // per-channel column of W_bond (L1-resident broadcast)
    float wb[BF];
#pragma unroll
    for (int k = 0; k < BF; k++) wb[k] = Wb[(size_t)k * C + t];
    float bbt = bb[t];

    float acc = 0.0f;
    if (g == 0) {                            // self-loop: emb=0, weight=1
        float xv = USEBF ? __bfloat162float(xb[(size_t)n * C + t]) : x[(size_t)n * C + t];
        acc = gelu_exact(xv) * (ir[n] * icn);
    }

    int o0 = off[n], o1 = off[n + 1];
    for (int i = o0 + g; i < o1; i += 4) {
        int e = __builtin_amdgcn_readfirstlane(bucket[i]);  // wave-uniform -> s_load path
        int r = ei[e];
        float s = ir[r] * icn * ew[e];

        const float4* eap = (const float4*)(ea + (size_t)e * BF);
        float4 q0 = eap[0], q1 = eap[1], q2 = eap[2], q3 = eap[3];

        float emb = bbt;
        emb = fmaf(q0.x, wb[0], emb);  emb = fmaf(q0.y, wb[1], emb);
        emb = fmaf(q0.z, wb[2], emb);  emb = fmaf(q0.w, wb[3], emb);
        emb = fmaf(q1.x, wb[4], emb);  emb = fmaf(q1.y, wb[5], emb);
        emb = fmaf(q1.z, wb[6], emb);  emb = fmaf(q1.w, wb[7], emb);
        emb = fmaf(q2.x, wb[8], emb);  emb = fmaf(q2.y, wb[9], emb);
        emb = fmaf(q2.z, wb[10], emb); emb = fmaf(q2.w, wb[11], emb);
        emb = fmaf(q3.x, wb[12], emb); emb = fmaf(q3.y, wb[13], emb);
        emb = fmaf(q3.z, wb[14], emb); emb = fmaf(q3.w, wb[15], emb);

        float xv = USEBF ? __bfloat162float(xb[(size_t)r * C + t]) : x[(size_t)r * C + t];
        acc = fmaf(gelu_exact(xv + emb), s, acc);
    }

    // epilogue: reduce 4 partials, then out[n] = vec @ W_lin + b_lin (k split 4-way)
    __shared__ float shp[4][C];
    __shared__ float shs[C];
    shp[g][t] = acc;
    __syncthreads();
    if (threadIdx.x < C) {
        int k = threadIdx.x;
        shs[k] = shp[0][k] + shp[1][k] + shp[2][k] + shp[3][k];
    }
    __syncthreads();
    float o = 0.0f;
    int k0 = g * 32;
#pragma unroll 8
    for (int j = 0; j < 32; j++) {
        int k = k0 + j;
        o = fmaf(shs[k], Wl[(size_t)k * C + t], o);
    }
    shp[g][t] = o;
    __syncthreads();
    if (threadIdx.x < C) {
        int c = threadIdx.x;
        out[(size_t)n * C + c] = bl[c] + shp[0][c] + shp[1][c] + shp[2][c] + shp[3][c];
    }
}

extern "C" void kernel_launch(void* const* d_in, const int* in_sizes, int n_in,
                              void* d_out, int out_size, void* d_ws, size_t ws_size,
                              hipStream_t stream) {
    const float* x  = (const float*)d_in[0];
    const float* ea = (const float*)d_in[1];
    const float* ew = (const float*)d_in[2];
    const float* Wb = (const float*)d_in[3];
    const float* bb = (const float*)d_in[4];
    const float* Wl = (const float*)d_in[5];
    const float* bl = (const float*)d_in[6];
    const int*   ei = (const int*)d_in[7];
    float* out = (float*)d_out;

    // workspace layout (u32 units):
    //   [xb 640000 u32 (bf16 x, optional)] bucket 640000 | off 10304 |
    //   dr 10240 | dc 10240 | cur 10240 | ir 10240 | ic 10240
    const size_t need_bf = (size_t)(640000 + 640000 + 10304 + 5 * 10240) * 4;
    bool usebf = ws_size >= need_bf;

    unsigned* w32 = (unsigned*)d_ws;
    __hip_bfloat16* xb = (__hip_bfloat16*)w32;
    int* bucket = (int*)(w32 + (usebf ? 640000 : 0));
    int* off    = bucket + 640000;
    int* dr     = off + 10304;
    int* dc     = dr + 10240;
    int* cur    = dc + 10240;
    float* ir   = (float*)(cur + 10240);
    float* ic   = ir + 10240;

    hipMemsetAsync(dr, 0, 3 * 10240 * sizeof(int), stream);   // dr, dc, cur
    if (usebf) k_cvt<<<1250, 256, 0, stream>>>(x, xb);
    k_deg<<<(N_EDGES + 255) / 256, 256, 0, stream>>>(ei, dr, dc);
    k_scan<<<1, 1024, 0, stream>>>(dr, dc, off, ir, ic);
    k_scatter<<<(N_EDGES + 255) / 256, 256, 0, stream>>>(ei, off, cur, bucket);
    if (usebf)
        k_node<true><<<N_NODES, 512, 0, stream>>>(x, xb, ea, ew, Wb, bb, ei, ir, ic, off, bucket, Wl, bl, out);
    else
        k_node<false><<<N_NODES, 512, 0, stream>>>(x, xb, ea, ew, Wb, bb, ei, ir, ic, off, bucket, Wl, bl, out);
}